// Round 16
// baseline (204.824 us; speedup 1.0000x reference)
//
#include <hip/hip_runtime.h>
#include <math.h>
#include <stdint.h>

#define H 64
#define FIN 39
#define PB 256        // partition blocks (must be 256: scan-block fold uses >>8)
#define NRSH 9        // nodes per bucket = 512
#define NBUK_MAX 256

typedef _Float16 half8 __attribute__((ext_vector_type(8)));
typedef _Float16 half4 __attribute__((ext_vector_type(4)));
typedef float floatx4 __attribute__((ext_vector_type(4)));

// ---- phase 1: per-(bucket,block) histogram ----
__global__ void k_hist(const int* __restrict__ col, int* __restrict__ hist,
                       int E, int nbuk, int chunk) {
    __shared__ int hc[NBUK_MAX];
    int b = blockIdx.x;
    for (int i = threadIdx.x; i < nbuk; i += 256) hc[i] = 0;
    __syncthreads();
    int lo = b * chunk, hi = min(E, lo + chunk);
    for (int e = lo + threadIdx.x; e < hi; e += 256)
        atomicAdd(&hc[col[e] >> NRSH], 1);
    __syncthreads();
    for (int i = threadIdx.x; i < nbuk; i += 256) hist[i * PB + b] = hc[i];
}

// ---- per-block scan + bsum ----
__global__ void k_scanA(const int* __restrict__ in, int* __restrict__ out,
                        int* __restrict__ bsum, int M) {
    __shared__ int lds[256];
    int tid = threadIdx.x;
    int i = blockIdx.x * 256 + tid;
    int v = (i < M) ? in[i] : 0;
    lds[tid] = v;
    __syncthreads();
    int acc = v;
    for (int off = 1; off < 256; off <<= 1) {
        int t = (tid >= off) ? lds[tid - off] : 0;
        __syncthreads();
        acc += t;
        lds[tid] = acc;
        __syncthreads();
    }
    if (i < M) out[i] = acc - v;
    if (tid == 255) bsum[blockIdx.x] = acc;
}

// ---- scan of block sums (nb <= 512) ----
__global__ void k_scan2(int* __restrict__ bsum, int nb) {
    __shared__ int lds[512];
    int tid = threadIdx.x;
    int v = (tid < nb) ? bsum[tid] : 0;
    lds[tid] = v;
    __syncthreads();
    int acc = v;
    for (int off = 1; off < 512; off <<= 1) {
        int t = (tid >= off) ? lds[tid - off] : 0;
        __syncthreads();
        acc += t;
        lds[tid] = acc;
        __syncthreads();
    }
    if (tid < nb) bsum[tid] = acc - v;
}

// ---- phase 3: scatter edges into bucket-partitioned PACKED pair array ----
// packed = (local_c 9b) << 23 | r (r < 2^23). scanC folded: base += bsum[g>>8].
__global__ void k_part(const int* __restrict__ row, const int* __restrict__ col,
                       const int* __restrict__ hscan, const int* __restrict__ bsum,
                       uint32_t* __restrict__ upairs, int E, int nbuk, int chunk) {
    __shared__ int cur[NBUK_MAX];
    int b = blockIdx.x;
    for (int i = threadIdx.x; i < nbuk; i += 256) {
        int g = i * PB + b;
        cur[i] = hscan[g] + bsum[g >> 8];
    }
    __syncthreads();
    int lo = b * chunk, hi = min(E, lo + chunk);
    for (int e = lo + threadIdx.x; e < hi; e += 256) {
        int c = col[e];
        int r = row[e];
        int pos = atomicAdd(&cur[c >> NRSH], 1);
        upairs[pos] = ((uint32_t)(c & 511) << 23) | (uint32_t)r;
    }
}

// ---- phase 4: one block per bucket: LDS deg-hist -> scan -> startv/deg/cnt -> fill ----
__global__ __launch_bounds__(256) void k_fillb(const uint32_t* __restrict__ upairs,
        const int* __restrict__ hscan, const int* __restrict__ bsum,
        int* __restrict__ csr, int* __restrict__ startv, int* __restrict__ deg,
        float* __restrict__ cnt, int E, int N, int nbuk) {
    __shared__ int dh[512];
    __shared__ int sc[256];
    int b = blockIdx.x;
    int tid = threadIdx.x;
    int nlo = b << NRSH;
    int g0 = b * PB;
    int s0 = hscan[g0] + bsum[g0 >> 8];
    int e0;
    if (b == nbuk - 1) e0 = E;
    else {
        int g1 = (b + 1) * PB;
        e0 = hscan[g1] + bsum[g1 >> 8];
    }
    dh[tid] = 0; dh[tid + 256] = 0;
    __syncthreads();
    for (int i = s0 + tid; i < e0; i += 256)
        atomicAdd(&dh[upairs[i] >> 23], 1);
    __syncthreads();
    int v0 = dh[2 * tid], v1 = dh[2 * tid + 1];
    int ps = v0 + v1;
    sc[tid] = ps;
    __syncthreads();
    int acc = ps;
    for (int off = 1; off < 256; off <<= 1) {
        int t = (tid >= off) ? sc[tid - off] : 0;
        __syncthreads();
        acc += t;
        sc[tid] = acc;
        __syncthreads();
    }
    int excl = acc - ps;
    int o0 = excl, o1 = excl + v0;
    int n0 = nlo + 2 * tid, n1 = n0 + 1;
    if (n0 < N) { startv[n0] = s0 + o0; deg[n0] = v0; cnt[n0] = (float)v0; }
    if (n1 < N) { startv[n1] = s0 + o1; deg[n1] = v1; cnt[n1] = (float)v1; }
    __syncthreads();
    dh[2 * tid] = o0;
    dh[2 * tid + 1] = o1;
    __syncthreads();
    for (int i = s0 + tid; i < e0; i += 256) {
        uint32_t p = upairs[i];
        int pos = atomicAdd(&dh[p >> 23], 1);
        csr[s0 + pos] = (int)(p & 0x7FFFFF);
    }
}

// ---- fused weight prep: grid 7.
// blk 0,1: pack updW[l]_top + I -> ppk[0,1]
// blk 2,3: Wagg[l] = Wm_top@Wu_bot computed on the fly -> ppk[2,3]
// blk 4,5: Wcomb[l] = Wm_bot@Wu_bot on the fly -> ppk[4,5]
// blk 6:   opk (W1) + bcomb[l] = msg_b@Wu_bot
__global__ void k_prep(const float* __restrict__ msgW, const float* __restrict__ msgb,
                       const float* __restrict__ updW, const float* __restrict__ W1,
                       _Float16* __restrict__ ppk, _Float16* __restrict__ opk,
                       float* __restrict__ bcomb) {
    int mat = blockIdx.x;
    if (mat < 6) {
        int l = mat & 1;
        _Float16* dst = ppk + (size_t)mat * 8 * 64 * 8;
        const float* Wu = updW + (size_t)l * 2 * H * H + H * H;
        for (int e = threadIdx.x; e < 8 * 64; e += 256) {
            int fidx = e >> 6;
            int ln = e & 63;
            int s = fidx >> 2, t = fidx & 3;
            int kbase = s * 32 + ((ln >> 4) * 8);
            int c = t * 16 + (ln & 15);
            _Float16* d = dst + (size_t)e * 8;
            if (mat < 2) {
                const float* W = updW + (size_t)l * 2 * H * H;  // top half
                #pragma unroll
                for (int i = 0; i < 8; ++i) {
                    float v = W[(size_t)(kbase + i) * H + c];
                    if ((kbase + i) == c) v += 1.0f;
                    d[i] = (_Float16)v;
                }
            } else {
                const float* Wm = (mat < 4) ? (msgW + (size_t)l * 2 * H * H)
                                            : (msgW + (size_t)l * 2 * H * H + H * H);
                #pragma unroll
                for (int i = 0; i < 8; ++i) {
                    const float* wr = Wm + (size_t)(kbase + i) * H;
                    float s2 = 0.f;
                    for (int k = 0; k < H; ++k) s2 += wr[k] * Wu[k * H + c];
                    d[i] = (_Float16)s2;
                }
            }
        }
    } else {
        // opk: 4 frags of W1 [64][32]
        for (int e = threadIdx.x; e < 4 * 64; e += 256) {
            int fidx = e >> 6;
            int ln = e & 63;
            int s = fidx >> 1, t = fidx & 1;
            int kbase = s * 32 + ((ln >> 4) * 8);
            int c = t * 16 + (ln & 15);
            _Float16* d = opk + (size_t)e * 8;
            #pragma unroll
            for (int i = 0; i < 8; ++i)
                d[i] = (_Float16)W1[(size_t)(kbase + i) * 32 + c];
        }
        // bcomb
        if (threadIdx.x < 128) {
            int l = threadIdx.x >> 6;
            int j = threadIdx.x & 63;
            const float* Wu = updW + (size_t)l * 2 * H * H + H * H;
            const float* mb = msgb + (size_t)l * H;
            float s = 0.f;
            for (int k = 0; k < H; ++k) s += mb[k] * Wu[k * H + j];
            bcomb[(size_t)l * H + j] = s;
        }
    }
}

// ---- h16 = fp16(x @ W_in + b_in) ----
__global__ void k_input(const float* __restrict__ x, const float* __restrict__ Win,
                        const float* __restrict__ bin, _Float16* __restrict__ h16, int N) {
    __shared__ float w[FIN * H];
    int tid = threadIdx.x;
    for (int i = tid; i < FIN * H; i += 512) w[i] = Win[i];
    __syncthreads();
    int j = tid & 63;
    int un = __builtin_amdgcn_readfirstlane(blockIdx.x * 32 + (tid >> 6) * 4);
    int n0 = min(un, N - 1), n1 = min(un + 1, N - 1), n2 = min(un + 2, N - 1), n3 = min(un + 3, N - 1);
    const float* x0 = x + (size_t)n0 * FIN;
    const float* x1 = x + (size_t)n1 * FIN;
    const float* x2 = x + (size_t)n2 * FIN;
    const float* x3 = x + (size_t)n3 * FIN;
    float a0 = 0.f, a1 = 0.f, a2 = 0.f, a3 = 0.f;
    #pragma unroll
    for (int k = 0; k < FIN; ++k) {
        float wv = w[k * H + j];
        a0 += x0[k] * wv;
        a1 += x1[k] * wv;
        a2 += x2[k] * wv;
        a3 += x3[k] * wv;
    }
    float bj = bin[j];
    if (un     < N) h16[(size_t)n0 * H + j] = (_Float16)(a0 + bj);
    if (un + 1 < N) h16[(size_t)n1 * H + j] = (_Float16)(a1 + bj);
    if (un + 2 < N) h16[(size_t)n2 * H + j] = (_Float16)(a2 + bj);
    if (un + 3 < N) h16[(size_t)n3 * H + j] = (_Float16)(a3 + bj);
}

// ---- aggr gather: S[n] = raw fp16 sum of h16[src] rows (ROOFLINE-certified r15) ----
__global__ void k_aggr(const int* __restrict__ startv, const int* __restrict__ deg,
                       const int* __restrict__ csr, const _Float16* __restrict__ A,
                       _Float16* __restrict__ z16, int N) {
    int tid = threadIdx.x;
    int n = __builtin_amdgcn_readfirstlane(blockIdx.x * 4 + (tid >> 6));
    if (n >= N) return;
    int l = tid & 63;
    int q = l >> 4;
    int m = l & 15;
    int s = startv[n];
    int d = deg[n];
    float a0 = 0.f, a1 = 0.f, a2 = 0.f, a3 = 0.f;
    int i = 0;
    for (; i + 16 <= d; i += 16) {
        int r0 = csr[s + i + q];
        int r1 = csr[s + i + 4 + q];
        int r2 = csr[s + i + 8 + q];
        int r3 = csr[s + i + 12 + q];
        half4 h0 = *(const half4*)(A + (size_t)r0 * H + m * 4);
        half4 h1 = *(const half4*)(A + (size_t)r1 * H + m * 4);
        half4 h2 = *(const half4*)(A + (size_t)r2 * H + m * 4);
        half4 h3 = *(const half4*)(A + (size_t)r3 * H + m * 4);
        a0 += ((float)h0[0] + (float)h1[0]) + ((float)h2[0] + (float)h3[0]);
        a1 += ((float)h0[1] + (float)h1[1]) + ((float)h2[1] + (float)h3[1]);
        a2 += ((float)h0[2] + (float)h1[2]) + ((float)h2[2] + (float)h3[2]);
        a3 += ((float)h0[3] + (float)h1[3]) + ((float)h2[3] + (float)h3[3]);
    }
    for (; i + 8 <= d; i += 8) {
        int rA = csr[s + i + q];
        int rB = csr[s + i + 4 + q];
        half4 hA = *(const half4*)(A + (size_t)rA * H + m * 4);
        half4 hB = *(const half4*)(A + (size_t)rB * H + m * 4);
        a0 += (float)hA[0] + (float)hB[0];
        a1 += (float)hA[1] + (float)hB[1];
        a2 += (float)hA[2] + (float)hB[2];
        a3 += (float)hA[3] + (float)hB[3];
    }
    for (; i < d; i += 4) {
        int ii = i + q;
        if (ii < d) {
            int r = csr[s + ii];
            half4 hv = *(const half4*)(A + (size_t)r * H + m * 4);
            a0 += (float)hv[0];
            a1 += (float)hv[1];
            a2 += (float)hv[2];
            a3 += (float)hv[3];
        }
    }
    a0 += __shfl_xor(a0, 16); a0 += __shfl_xor(a0, 32);
    a1 += __shfl_xor(a1, 16); a1 += __shfl_xor(a1, 32);
    a2 += __shfl_xor(a2, 16); a2 += __shfl_xor(a2, 32);
    a3 += __shfl_xor(a3, 16); a3 += __shfl_xor(a3, 32);
    if (q == 0) {
        half4 hv;
        hv[0] = (_Float16)a0; hv[1] = (_Float16)a1;
        hv[2] = (_Float16)a2; hv[3] = (_Float16)a3;
        *(half4*)(z16 + (size_t)n * H + m * 4) = hv;
    }
}

// ---- MFMA upd: h@(Wu_top+I) + rd*(S@Wagg) + mask*(h@Wcomb + bcomb) + LN ----
template<bool DO_OUT>
__global__ __launch_bounds__(256) void k_upd(const _Float16* __restrict__ h16in,
        const _Float16* __restrict__ z16, const float* __restrict__ cnt,
        const _Float16* __restrict__ apk, const _Float16* __restrict__ gpk,
        const _Float16* __restrict__ cpk, const _Float16* __restrict__ opk,
        const float* __restrict__ bias, const float* __restrict__ bcomb,
        const float* __restrict__ lng, const float* __restrict__ lnb,
        _Float16* __restrict__ h16out,
        const float* __restrict__ b1, const float* __restrict__ W2,
        const float* __restrict__ b2,
        float* __restrict__ out, int N) {
    __shared__ __align__(16) _Float16 hsall[DO_OUT ? 4 * 16 * 72 : 8];
    int l = threadIdx.x & 63;
    int w = threadIdx.x >> 6;
    int n0 = blockIdx.x * 64 + w * 16;
    int mrow = l & 15, kgrp = l >> 4;
    int nA = min(n0 + mrow, N - 1);
    half8 ah0 = *(const half8*)(h16in + (size_t)nA * H + kgrp * 8);
    half8 ah1 = *(const half8*)(h16in + (size_t)nA * H + 32 + kgrp * 8);
    half8 zf0 = *(const half8*)(z16 + (size_t)nA * H + kgrp * 8);
    half8 zf1 = *(const half8*)(z16 + (size_t)nA * H + 32 + kgrp * 8);
    floatx4 acc[4] = {};
    floatx4 accZ[4] = {};
    floatx4 accC[4] = {};
    #pragma unroll
    for (int s = 0; s < 2; ++s) {
        half8 a = s ? ah1 : ah0;
        half8 z = s ? zf1 : zf0;
        #pragma unroll
        for (int t = 0; t < 4; ++t) {
            half8 bt = *(const half8*)(apk + ((size_t)((s * 4 + t) * 64 + l)) * 8);
            half8 bg = *(const half8*)(gpk + ((size_t)((s * 4 + t) * 64 + l)) * 8);
            half8 bc = *(const half8*)(cpk + ((size_t)((s * 4 + t) * 64 + l)) * 8);
            acc[t]  = __builtin_amdgcn_mfma_f32_16x16x32_f16(a, bt, acc[t], 0, 0, 0);
            accZ[t] = __builtin_amdgcn_mfma_f32_16x16x32_f16(z, bg, accZ[t], 0, 0, 0);
            accC[t] = __builtin_amdgcn_mfma_f32_16x16x32_f16(a, bc, accC[t], 0, 0, 0);
        }
    }
    float bl[4], gl[4], bb2[4], bcl[4];
    #pragma unroll
    for (int t = 0; t < 4; ++t) {
        int j = t * 16 + mrow;
        bl[t] = bias[j]; gl[t] = lng[j]; bb2[t] = lnb[j]; bcl[t] = bcomb[j];
    }
    float4 cnt4 = *(const float4*)(cnt + n0 + kgrp * 4);
    float zt[4][4];
    #pragma unroll
    for (int r = 0; r < 4; ++r) {
        float c = (r == 0) ? cnt4.x : (r == 1) ? cnt4.y : (r == 2) ? cnt4.z : cnt4.w;
        float rdn = 1.0f / fmaxf(c, 1.0f);
        float mk = (c > 0.f) ? 1.0f : 0.0f;
        #pragma unroll
        for (int t = 0; t < 4; ++t)
            zt[t][r] = acc[t][r] + rdn * accZ[t][r] + mk * (accC[t][r] + bcl[t]) + bl[t];
    }
    #pragma unroll
    for (int r = 0; r < 4; ++r) {
        float s = zt[0][r] + zt[1][r] + zt[2][r] + zt[3][r];
        s += __shfl_xor(s, 1); s += __shfl_xor(s, 2);
        s += __shfl_xor(s, 4); s += __shfl_xor(s, 8);
        float mu = s * (1.0f / H);
        float v = 0.f;
        #pragma unroll
        for (int t = 0; t < 4; ++t) { float d = zt[t][r] - mu; v += d * d; }
        v += __shfl_xor(v, 1); v += __shfl_xor(v, 2);
        v += __shfl_xor(v, 4); v += __shfl_xor(v, 8);
        float rinv = rsqrtf(v * (1.0f / H) + 1e-5f);
        int m = kgrp * 4 + r;
        int n = n0 + m;
        #pragma unroll
        for (int t = 0; t < 4; ++t) {
            float hval = (zt[t][r] - mu) * rinv * gl[t] + bb2[t];
            if (DO_OUT) hsall[(w * 16 + m) * 72 + t * 16 + mrow] = (_Float16)hval;
            else if (n < N) h16out[(size_t)n * H + t * 16 + mrow] = (_Float16)hval;
        }
    }
    if (DO_OUT) {
        __syncthreads();
        const _Float16* hs = hsall + w * 16 * 72;
        half8 af0 = *(const half8*)(hs + mrow * 72 + kgrp * 8);
        half8 af1 = *(const half8*)(hs + mrow * 72 + 32 + kgrp * 8);
        floatx4 accO[2] = {};
        #pragma unroll
        for (int s = 0; s < 2; ++s) {
            half8 a = s ? af1 : af0;
            #pragma unroll
            for (int t = 0; t < 2; ++t) {
                half8 b = *(const half8*)(opk + ((size_t)((s * 2 + t) * 64 + l)) * 8);
                accO[t] = __builtin_amdgcn_mfma_f32_16x16x32_f16(a, b, accO[t], 0, 0, 0);
            }
        }
        float b1v0 = b1[mrow], b1v1 = b1[16 + mrow];
        float w2v0 = W2[mrow], w2v1 = W2[16 + mrow];
        float b2v = b2[0];
        #pragma unroll
        for (int r = 0; r < 4; ++r) {
            float t0 = accO[0][r] + b1v0;
            float t1 = accO[1][r] + b1v1;
            float g = 0.5f * t0 * (1.0f + erff(t0 * 0.70710678118654752f)) * w2v0
                    + 0.5f * t1 * (1.0f + erff(t1 * 0.70710678118654752f)) * w2v1;
            g += __shfl_xor(g, 1); g += __shfl_xor(g, 2);
            g += __shfl_xor(g, 4); g += __shfl_xor(g, 8);
            int n = n0 + kgrp * 4 + r;
            if (mrow == 0 && n < N) out[n] = 1.0f / (1.0f + expf(-(g + b2v)));
        }
    }
}

extern "C" void kernel_launch(void* const* d_in, const int* in_sizes, int n_in,
                              void* d_out, int out_size, void* d_ws, size_t ws_size,
                              hipStream_t stream) {
    const float* x    = (const float*)d_in[0];
    const int*   ei   = (const int*)d_in[1];
    const float* Win  = (const float*)d_in[2];
    const float* bin  = (const float*)d_in[3];
    const float* msgW = (const float*)d_in[4];
    const float* msgb = (const float*)d_in[5];
    const float* updW = (const float*)d_in[6];
    const float* updb = (const float*)d_in[7];
    const float* lng  = (const float*)d_in[8];
    const float* lnb  = (const float*)d_in[9];
    const float* W1   = (const float*)d_in[10];
    const float* b1   = (const float*)d_in[11];
    const float* W2   = (const float*)d_in[12];
    const float* b2   = (const float*)d_in[13];

    int N = in_sizes[0] / FIN;
    int E = in_sizes[1] / 2;
    const int* row = ei;
    const int* col = ei + E;

    int nbuk = (N + 511) >> NRSH;
    int M = nbuk * PB;
    int chunk = (E + PB - 1) / PB;

    float* wsp   = (float*)d_ws;
    float* cnt   = wsp;                              // N f32 (16B-aligned base)
    float* bcomb = wsp + N;                          // 2*H f32
    _Float16* Z16  = (_Float16*)(bcomb + 2 * H);     // N*H f16 (raw h edge-sum)
    _Float16* h16a = Z16 + (size_t)N * H;            // N*H f16
    _Float16* h16b = h16a + (size_t)N * H;           // N*H f16
    _Float16* ppk  = h16b + (size_t)N * H;           // 6*4096 halves
    _Float16* opk  = ppk + 6 * 4096;                 // 2048 halves
    int* deg    = (int*)(opk + 2048);                // N
    int* startv = deg + N;                           // N
    int* bsum   = startv + N;                        // 512
    int* hist   = bsum + 512;                        // M
    int* hscan  = hist + M;                          // M
    int* csr    = hscan + M;                         // E
    uint32_t* upairs = (uint32_t*)(csr + E);         // E uint

    int nb64 = (N + 63) / 64;
    int scanblk = (M + 255) / 256;                   // = nbuk

    k_prep<<<7, 256, 0, stream>>>(msgW, msgb, updW, W1, ppk, opk, bcomb);

    // two-level radix CSR build (packed pairs, scanC folded into consumers)
    k_hist<<<PB, 256, 0, stream>>>(col, hist, E, nbuk, chunk);
    k_scanA<<<scanblk, 256, 0, stream>>>(hist, hscan, bsum, M);
    k_scan2<<<1, 512, 0, stream>>>(bsum, scanblk);
    k_part<<<PB, 256, 0, stream>>>(row, col, hscan, bsum, upairs, E, nbuk, chunk);
    k_fillb<<<nbuk, 256, 0, stream>>>(upairs, hscan, bsum, csr, startv, deg, cnt,
                                      E, N, nbuk);

    k_input<<<(N + 31) / 32, 512, 0, stream>>>(x, Win, bin, h16a, N);

    // layer 0
    k_aggr<<<(N + 3) / 4, 256, 0, stream>>>(startv, deg, csr, h16a, Z16, N);
    k_upd<false><<<nb64, 256, 0, stream>>>(h16a, Z16, cnt,
                                           ppk + 0 * 4096, ppk + 2 * 4096, ppk + 4 * 4096,
                                           nullptr, updb, bcomb, lng, lnb, h16b,
                                           nullptr, nullptr, nullptr, nullptr, N);

    // layer 1 (fused MFMA out-MLP -> d_out)
    k_aggr<<<(N + 3) / 4, 256, 0, stream>>>(startv, deg, csr, h16b, Z16, N);
    k_upd<true><<<nb64, 256, 0, stream>>>(h16b, Z16, cnt,
                                          ppk + 1 * 4096, ppk + 3 * 4096, ppk + 5 * 4096,
                                          opk, updb + H, bcomb + H, lng + H, lnb + H,
                                          nullptr, b1, W2, b2, (float*)d_out, N);
}

// Round 17
// 190.541 us; speedup vs baseline: 1.0750x; 1.0750x over previous
//
#include <hip/hip_runtime.h>
#include <math.h>
#include <stdint.h>

#define H 64
#define FIN 39
#define PB 512        // partition blocks
#define NRSH 9        // nodes per bucket = 512
#define NBUK_MAX 256

typedef _Float16 half8 __attribute__((ext_vector_type(8)));
typedef _Float16 half4 __attribute__((ext_vector_type(4)));
typedef float floatx4 __attribute__((ext_vector_type(4)));

// ---- phase 1: per-(bucket,block) histogram ----
__global__ void k_hist(const int* __restrict__ col, int* __restrict__ hist,
                       int E, int nbuk, int chunk) {
    __shared__ int hc[NBUK_MAX];
    int b = blockIdx.x;
    for (int i = threadIdx.x; i < nbuk; i += 256) hc[i] = 0;
    __syncthreads();
    int lo = b * chunk, hi = min(E, lo + chunk);
    for (int e = lo + threadIdx.x; e < hi; e += 256)
        atomicAdd(&hc[col[e] >> NRSH], 1);
    __syncthreads();
    for (int i = threadIdx.x; i < nbuk; i += 256) hist[i * PB + b] = hc[i];
}

// ---- per-block scan (256-elem chunks) + bsum ----
__global__ void k_scanA(const int* __restrict__ in, int* __restrict__ out,
                        int* __restrict__ bsum, int M) {
    __shared__ int lds[256];
    int tid = threadIdx.x;
    int i = blockIdx.x * 256 + tid;
    int v = (i < M) ? in[i] : 0;
    lds[tid] = v;
    __syncthreads();
    int acc = v;
    for (int off = 1; off < 256; off <<= 1) {
        int t = (tid >= off) ? lds[tid - off] : 0;
        __syncthreads();
        acc += t;
        lds[tid] = acc;
        __syncthreads();
    }
    if (i < M) out[i] = acc - v;
    if (tid == 255) bsum[blockIdx.x] = acc;
}

// ---- scan of block sums (nb <= 512) ----
__global__ void k_scan2(int* __restrict__ bsum, int nb) {
    __shared__ int lds[512];
    int tid = threadIdx.x;
    int v = (tid < nb) ? bsum[tid] : 0;
    lds[tid] = v;
    __syncthreads();
    int acc = v;
    for (int off = 1; off < 512; off <<= 1) {
        int t = (tid >= off) ? lds[tid - off] : 0;
        __syncthreads();
        acc += t;
        lds[tid] = acc;
        __syncthreads();
    }
    if (tid < nb) bsum[tid] = acc - v;
}

// ---- phase 3: scatter into bucket-partitioned PACKED pair array ----
// packed = (local_c 9b) << 23 | r. Global base = hscan[g] + bsum[g>>8] (scanC folded).
__global__ void k_part(const int* __restrict__ row, const int* __restrict__ col,
                       const int* __restrict__ hscan, const int* __restrict__ bsum,
                       uint32_t* __restrict__ upairs, int E, int nbuk, int chunk) {
    __shared__ int cur[NBUK_MAX];
    int b = blockIdx.x;
    for (int i = threadIdx.x; i < nbuk; i += 256) {
        int g = i * PB + b;
        cur[i] = hscan[g] + bsum[g >> 8];
    }
    __syncthreads();
    int lo = b * chunk, hi = min(E, lo + chunk);
    for (int e = lo + threadIdx.x; e < hi; e += 256) {
        int c = col[e];
        int r = row[e];
        int pos = atomicAdd(&cur[c >> NRSH], 1);
        upairs[pos] = ((uint32_t)(c & 511) << 23) | (uint32_t)r;
    }
}

// ---- phase 4: one block per bucket: LDS deg-hist -> scan -> startv/deg/cnt -> fill ----
__global__ __launch_bounds__(256) void k_fillb(const uint32_t* __restrict__ upairs,
        const int* __restrict__ hscan, const int* __restrict__ bsum,
        int* __restrict__ csr, int* __restrict__ startv, int* __restrict__ deg,
        float* __restrict__ cnt, int E, int N, int nbuk) {
    __shared__ int dh[512];
    __shared__ int sc[256];
    int b = blockIdx.x;
    int tid = threadIdx.x;
    int nlo = b << NRSH;
    int g0 = b * PB;
    int s0 = hscan[g0] + bsum[g0 >> 8];
    int e0;
    if (b == nbuk - 1) e0 = E;
    else {
        int g1 = (b + 1) * PB;
        e0 = hscan[g1] + bsum[g1 >> 8];
    }
    dh[tid] = 0; dh[tid + 256] = 0;
    __syncthreads();
    for (int i = s0 + tid; i < e0; i += 256)
        atomicAdd(&dh[upairs[i] >> 23], 1);
    __syncthreads();
    int v0 = dh[2 * tid], v1 = dh[2 * tid + 1];
    int ps = v0 + v1;
    sc[tid] = ps;
    __syncthreads();
    int acc = ps;
    for (int off = 1; off < 256; off <<= 1) {
        int t = (tid >= off) ? sc[tid - off] : 0;
        __syncthreads();
        acc += t;
        sc[tid] = acc;
        __syncthreads();
    }
    int excl = acc - ps;
    int o0 = excl, o1 = excl + v0;
    int n0 = nlo + 2 * tid, n1 = n0 + 1;
    if (n0 < N) { startv[n0] = s0 + o0; deg[n0] = v0; cnt[n0] = (float)v0; }
    if (n1 < N) { startv[n1] = s0 + o1; deg[n1] = v1; cnt[n1] = (float)v1; }
    __syncthreads();
    dh[2 * tid] = o0;
    dh[2 * tid + 1] = o1;
    __syncthreads();
    for (int i = s0 + tid; i < e0; i += 256) {
        uint32_t p = upairs[i];
        int pos = atomicAdd(&dh[p >> 23], 1);
        csr[s0 + pos] = (int)(p & 0x7FFFFF);
    }
}

// ---- Wagg = Wm_top @ Wu_bot; Wcomb = Wm_bot @ Wu_bot; bcomb = msg_b @ Wu_bot ----
// grid 32: blockIdx = l*16 + rowgroup (r15-proven layout)
__global__ void k_comb(const float* __restrict__ msgW, const float* __restrict__ msgb,
                       const float* __restrict__ updW, float* __restrict__ waggr,
                       float* __restrict__ wcomb, float* __restrict__ bcomb) {
    int l = blockIdx.x >> 4;
    int rg = blockIdx.x & 15;
    const float* Wmt = msgW + (size_t)l * 2 * H * H;
    const float* Wmb = Wmt + H * H;
    const float* Wu  = updW + (size_t)l * 2 * H * H + H * H;
    const float* mb  = msgb + (size_t)l * H;
    float* WA = waggr + (size_t)l * H * H;
    float* WC = wcomb + (size_t)l * H * H;
    int i = rg * 4 + (threadIdx.x >> 6);
    int j = threadIdx.x & 63;
    float sa = 0.f, sc = 0.f;
    #pragma unroll 8
    for (int k = 0; k < H; ++k) {
        float wu = Wu[k * H + j];
        sa += Wmt[i * H + k] * wu;
        sc += Wmb[i * H + k] * wu;
    }
    WA[i * H + j] = sa;
    WC[i * H + j] = sc;
    if (rg == 0 && threadIdx.x < H) {
        int jj = threadIdx.x;
        float s = 0.f;
        #pragma unroll 8
        for (int k = 0; k < H; ++k) s += mb[k] * Wu[k * H + jj];
        bcomb[(size_t)l * H + jj] = s;
    }
}

// ---- pack six 64x64 mats -> 8 MFMA B-frags each ----
__global__ void k_pack6(const float* __restrict__ updW, const float* __restrict__ waggr,
                        const float* __restrict__ wcomb, _Float16* __restrict__ ppk) {
    int mat = blockIdx.x;
    const float* W;
    bool addI = false;
    if (mat < 2)      { W = updW + (size_t)mat * 2 * H * H; addI = true; }
    else if (mat < 4) { W = waggr + (size_t)(mat - 2) * H * H; }
    else              { W = wcomb + (size_t)(mat - 4) * H * H; }
    _Float16* dst = ppk + (size_t)mat * 8 * 64 * 8;
    for (int e = threadIdx.x; e < 8 * 64; e += 256) {
        int fidx = e >> 6;
        int ln = e & 63;
        int s = fidx >> 2, t = fidx & 3;
        int kbase = s * 32 + ((ln >> 4) * 8);
        int c = t * 16 + (ln & 15);
        _Float16* d = dst + (size_t)e * 8;
        #pragma unroll
        for (int i = 0; i < 8; ++i) {
            float v = W[(size_t)(kbase + i) * H + c];
            if (addI && (kbase + i) == c) v += 1.0f;
            d[i] = (_Float16)v;
        }
    }
}

// ---- pack W1 [64][32] fp32 -> 4 MFMA B-fragments fp16 ----
__global__ void k_packO(const float* __restrict__ W1, _Float16* __restrict__ opk) {
    for (int e = threadIdx.x; e < 4 * 64; e += 256) {
        int fidx = e >> 6;
        int ln = e & 63;
        int s = fidx >> 1, t = fidx & 1;
        int kbase = s * 32 + ((ln >> 4) * 8);
        int c = t * 16 + (ln & 15);
        _Float16* d = opk + (size_t)e * 8;
        #pragma unroll
        for (int i = 0; i < 8; ++i)
            d[i] = (_Float16)W1[(size_t)(kbase + i) * 32 + c];
    }
}

// ---- h16 = fp16(x @ W_in + b_in) ----
__global__ void k_input(const float* __restrict__ x, const float* __restrict__ Win,
                        const float* __restrict__ bin, _Float16* __restrict__ h16, int N) {
    __shared__ float w[FIN * H];
    int tid = threadIdx.x;
    for (int i = tid; i < FIN * H; i += 512) w[i] = Win[i];
    __syncthreads();
    int j = tid & 63;
    int un = __builtin_amdgcn_readfirstlane(blockIdx.x * 32 + (tid >> 6) * 4);
    int n0 = min(un, N - 1), n1 = min(un + 1, N - 1), n2 = min(un + 2, N - 1), n3 = min(un + 3, N - 1);
    const float* x0 = x + (size_t)n0 * FIN;
    const float* x1 = x + (size_t)n1 * FIN;
    const float* x2 = x + (size_t)n2 * FIN;
    const float* x3 = x + (size_t)n3 * FIN;
    float a0 = 0.f, a1 = 0.f, a2 = 0.f, a3 = 0.f;
    #pragma unroll
    for (int k = 0; k < FIN; ++k) {
        float wv = w[k * H + j];
        a0 += x0[k] * wv;
        a1 += x1[k] * wv;
        a2 += x2[k] * wv;
        a3 += x3[k] * wv;
    }
    float bj = bin[j];
    if (un     < N) h16[(size_t)n0 * H + j] = (_Float16)(a0 + bj);
    if (un + 1 < N) h16[(size_t)n1 * H + j] = (_Float16)(a1 + bj);
    if (un + 2 < N) h16[(size_t)n2 * H + j] = (_Float16)(a2 + bj);
    if (un + 3 < N) h16[(size_t)n3 * H + j] = (_Float16)(a3 + bj);
}

// ---- aggr gather: S[n] = raw fp16 sum of h16[src] rows (ROOFLINE-certified r15) ----
__global__ void k_aggr(const int* __restrict__ startv, const int* __restrict__ deg,
                       const int* __restrict__ csr, const _Float16* __restrict__ A,
                       _Float16* __restrict__ z16, int N) {
    int tid = threadIdx.x;
    int n = __builtin_amdgcn_readfirstlane(blockIdx.x * 4 + (tid >> 6));
    if (n >= N) return;
    int l = tid & 63;
    int q = l >> 4;
    int m = l & 15;
    int s = startv[n];
    int d = deg[n];
    float a0 = 0.f, a1 = 0.f, a2 = 0.f, a3 = 0.f;
    int i = 0;
    for (; i + 16 <= d; i += 16) {
        int r0 = csr[s + i + q];
        int r1 = csr[s + i + 4 + q];
        int r2 = csr[s + i + 8 + q];
        int r3 = csr[s + i + 12 + q];
        half4 h0 = *(const half4*)(A + (size_t)r0 * H + m * 4);
        half4 h1 = *(const half4*)(A + (size_t)r1 * H + m * 4);
        half4 h2 = *(const half4*)(A + (size_t)r2 * H + m * 4);
        half4 h3 = *(const half4*)(A + (size_t)r3 * H + m * 4);
        a0 += ((float)h0[0] + (float)h1[0]) + ((float)h2[0] + (float)h3[0]);
        a1 += ((float)h0[1] + (float)h1[1]) + ((float)h2[1] + (float)h3[1]);
        a2 += ((float)h0[2] + (float)h1[2]) + ((float)h2[2] + (float)h3[2]);
        a3 += ((float)h0[3] + (float)h1[3]) + ((float)h2[3] + (float)h3[3]);
    }
    for (; i + 8 <= d; i += 8) {
        int rA = csr[s + i + q];
        int rB = csr[s + i + 4 + q];
        half4 hA = *(const half4*)(A + (size_t)rA * H + m * 4);
        half4 hB = *(const half4*)(A + (size_t)rB * H + m * 4);
        a0 += (float)hA[0] + (float)hB[0];
        a1 += (float)hA[1] + (float)hB[1];
        a2 += (float)hA[2] + (float)hB[2];
        a3 += (float)hA[3] + (float)hB[3];
    }
    for (; i < d; i += 4) {
        int ii = i + q;
        if (ii < d) {
            int r = csr[s + ii];
            half4 hv = *(const half4*)(A + (size_t)r * H + m * 4);
            a0 += (float)hv[0];
            a1 += (float)hv[1];
            a2 += (float)hv[2];
            a3 += (float)hv[3];
        }
    }
    a0 += __shfl_xor(a0, 16); a0 += __shfl_xor(a0, 32);
    a1 += __shfl_xor(a1, 16); a1 += __shfl_xor(a1, 32);
    a2 += __shfl_xor(a2, 16); a2 += __shfl_xor(a2, 32);
    a3 += __shfl_xor(a3, 16); a3 += __shfl_xor(a3, 32);
    if (q == 0) {
        half4 hv;
        hv[0] = (_Float16)a0; hv[1] = (_Float16)a1;
        hv[2] = (_Float16)a2; hv[3] = (_Float16)a3;
        *(half4*)(z16 + (size_t)n * H + m * 4) = hv;
    }
}

// ---- MFMA upd: h@(Wu_top+I) + rd*(S@Wagg) + mask*(h@Wcomb + bcomb) + LN ----
template<bool DO_OUT>
__global__ __launch_bounds__(256) void k_upd(const _Float16* __restrict__ h16in,
        const _Float16* __restrict__ z16, const float* __restrict__ cnt,
        const _Float16* __restrict__ apk, const _Float16* __restrict__ gpk,
        const _Float16* __restrict__ cpk, const _Float16* __restrict__ opk,
        const float* __restrict__ bias, const float* __restrict__ bcomb,
        const float* __restrict__ lng, const float* __restrict__ lnb,
        _Float16* __restrict__ h16out,
        const float* __restrict__ b1, const float* __restrict__ W2,
        const float* __restrict__ b2,
        float* __restrict__ out, int N) {
    __shared__ __align__(16) _Float16 hsall[DO_OUT ? 4 * 16 * 72 : 8];
    int l = threadIdx.x & 63;
    int w = threadIdx.x >> 6;
    int n0 = blockIdx.x * 64 + w * 16;
    int mrow = l & 15, kgrp = l >> 4;
    int nA = min(n0 + mrow, N - 1);
    half8 ah0 = *(const half8*)(h16in + (size_t)nA * H + kgrp * 8);
    half8 ah1 = *(const half8*)(h16in + (size_t)nA * H + 32 + kgrp * 8);
    half8 zf0 = *(const half8*)(z16 + (size_t)nA * H + kgrp * 8);
    half8 zf1 = *(const half8*)(z16 + (size_t)nA * H + 32 + kgrp * 8);
    floatx4 acc[4] = {};
    floatx4 accZ[4] = {};
    floatx4 accC[4] = {};
    #pragma unroll
    for (int s = 0; s < 2; ++s) {
        half8 a = s ? ah1 : ah0;
        half8 z = s ? zf1 : zf0;
        #pragma unroll
        for (int t = 0; t < 4; ++t) {
            half8 bt = *(const half8*)(apk + ((size_t)((s * 4 + t) * 64 + l)) * 8);
            half8 bg = *(const half8*)(gpk + ((size_t)((s * 4 + t) * 64 + l)) * 8);
            half8 bc = *(const half8*)(cpk + ((size_t)((s * 4 + t) * 64 + l)) * 8);
            acc[t]  = __builtin_amdgcn_mfma_f32_16x16x32_f16(a, bt, acc[t], 0, 0, 0);
            accZ[t] = __builtin_amdgcn_mfma_f32_16x16x32_f16(z, bg, accZ[t], 0, 0, 0);
            accC[t] = __builtin_amdgcn_mfma_f32_16x16x32_f16(a, bc, accC[t], 0, 0, 0);
        }
    }
    float bl[4], gl[4], bb2[4], bcl[4];
    #pragma unroll
    for (int t = 0; t < 4; ++t) {
        int j = t * 16 + mrow;
        bl[t] = bias[j]; gl[t] = lng[j]; bb2[t] = lnb[j]; bcl[t] = bcomb[j];
    }
    float4 cnt4 = *(const float4*)(cnt + n0 + kgrp * 4);
    float zt[4][4];
    #pragma unroll
    for (int r = 0; r < 4; ++r) {
        float c = (r == 0) ? cnt4.x : (r == 1) ? cnt4.y : (r == 2) ? cnt4.z : cnt4.w;
        float rdn = 1.0f / fmaxf(c, 1.0f);
        float mk = (c > 0.f) ? 1.0f : 0.0f;
        #pragma unroll
        for (int t = 0; t < 4; ++t)
            zt[t][r] = acc[t][r] + rdn * accZ[t][r] + mk * (accC[t][r] + bcl[t]) + bl[t];
    }
    #pragma unroll
    for (int r = 0; r < 4; ++r) {
        float s = zt[0][r] + zt[1][r] + zt[2][r] + zt[3][r];
        s += __shfl_xor(s, 1); s += __shfl_xor(s, 2);
        s += __shfl_xor(s, 4); s += __shfl_xor(s, 8);
        float mu = s * (1.0f / H);
        float v = 0.f;
        #pragma unroll
        for (int t = 0; t < 4; ++t) { float d = zt[t][r] - mu; v += d * d; }
        v += __shfl_xor(v, 1); v += __shfl_xor(v, 2);
        v += __shfl_xor(v, 4); v += __shfl_xor(v, 8);
        float rinv = rsqrtf(v * (1.0f / H) + 1e-5f);
        int m = kgrp * 4 + r;
        int n = n0 + m;
        #pragma unroll
        for (int t = 0; t < 4; ++t) {
            float hval = (zt[t][r] - mu) * rinv * gl[t] + bb2[t];
            if (DO_OUT) hsall[(w * 16 + m) * 72 + t * 16 + mrow] = (_Float16)hval;
            else if (n < N) h16out[(size_t)n * H + t * 16 + mrow] = (_Float16)hval;
        }
    }
    if (DO_OUT) {
        __syncthreads();
        const _Float16* hs = hsall + w * 16 * 72;
        half8 af0 = *(const half8*)(hs + mrow * 72 + kgrp * 8);
        half8 af1 = *(const half8*)(hs + mrow * 72 + 32 + kgrp * 8);
        floatx4 accO[2] = {};
        #pragma unroll
        for (int s = 0; s < 2; ++s) {
            half8 a = s ? af1 : af0;
            #pragma unroll
            for (int t = 0; t < 2; ++t) {
                half8 b = *(const half8*)(opk + ((size_t)((s * 2 + t) * 64 + l)) * 8);
                accO[t] = __builtin_amdgcn_mfma_f32_16x16x32_f16(a, b, accO[t], 0, 0, 0);
            }
        }
        float b1v0 = b1[mrow], b1v1 = b1[16 + mrow];
        float w2v0 = W2[mrow], w2v1 = W2[16 + mrow];
        float b2v = b2[0];
        #pragma unroll
        for (int r = 0; r < 4; ++r) {
            float t0 = accO[0][r] + b1v0;
            float t1 = accO[1][r] + b1v1;
            float g = 0.5f * t0 * (1.0f + erff(t0 * 0.70710678118654752f)) * w2v0
                    + 0.5f * t1 * (1.0f + erff(t1 * 0.70710678118654752f)) * w2v1;
            g += __shfl_xor(g, 1); g += __shfl_xor(g, 2);
            g += __shfl_xor(g, 4); g += __shfl_xor(g, 8);
            int n = n0 + kgrp * 4 + r;
            if (mrow == 0 && n < N) out[n] = 1.0f / (1.0f + expf(-(g + b2v)));
        }
    }
}

extern "C" void kernel_launch(void* const* d_in, const int* in_sizes, int n_in,
                              void* d_out, int out_size, void* d_ws, size_t ws_size,
                              hipStream_t stream) {
    const float* x    = (const float*)d_in[0];
    const int*   ei   = (const int*)d_in[1];
    const float* Win  = (const float*)d_in[2];
    const float* bin  = (const float*)d_in[3];
    const float* msgW = (const float*)d_in[4];
    const float* msgb = (const float*)d_in[5];
    const float* updW = (const float*)d_in[6];
    const float* updb = (const float*)d_in[7];
    const float* lng  = (const float*)d_in[8];
    const float* lnb  = (const float*)d_in[9];
    const float* W1   = (const float*)d_in[10];
    const float* b1   = (const float*)d_in[11];
    const float* W2   = (const float*)d_in[12];
    const float* b2   = (const float*)d_in[13];

    int N = in_sizes[0] / FIN;
    int E = in_sizes[1] / 2;
    const int* row = ei;
    const int* col = ei + E;

    int nbuk = (N + 511) >> NRSH;
    int M = nbuk * PB;
    int chunk = (E + PB - 1) / PB;

    float* wsp   = (float*)d_ws;
    float* cnt   = wsp;                              // N f32
    float* waggr = wsp + N;                          // 2*H*H f32
    float* wcomb = waggr + 2 * H * H;                // 2*H*H f32
    float* bcomb = wcomb + 2 * H * H;                // 2*H f32
    _Float16* Z16  = (_Float16*)(bcomb + 2 * H);     // N*H f16 (raw h edge-sum)
    _Float16* h16a = Z16 + (size_t)N * H;            // N*H f16
    _Float16* h16b = h16a + (size_t)N * H;           // N*H f16
    _Float16* ppk  = h16b + (size_t)N * H;           // 6*4096 halves
    _Float16* opk  = ppk + 6 * 4096;                 // 2048 halves
    int* deg    = (int*)(opk + 2048);                // N
    int* startv = deg + N;                           // N
    int* bsum   = startv + N;                        // 512
    int* hist   = bsum + 512;                        // M
    int* hscan  = hist + M;                          // M
    int* csr    = hscan + M;                         // E
    uint32_t* upairs = (uint32_t*)(csr + E);         // E uint

    int nb64 = (N + 63) / 64;
    int scanblk = (M + 255) / 256;                   // 392 <= 512

    k_comb<<<32, 256, 0, stream>>>(msgW, msgb, updW, waggr, wcomb, bcomb);
    k_pack6<<<6, 256, 0, stream>>>(updW, waggr, wcomb, ppk);
    k_packO<<<1, 256, 0, stream>>>(W1, opk);

    // two-level radix CSR build (packed pairs, scanC folded into consumers)
    k_hist<<<PB, 256, 0, stream>>>(col, hist, E, nbuk, chunk);
    k_scanA<<<scanblk, 256, 0, stream>>>(hist, hscan, bsum, M);
    k_scan2<<<1, 512, 0, stream>>>(bsum, scanblk);
    k_part<<<PB, 256, 0, stream>>>(row, col, hscan, bsum, upairs, E, nbuk, chunk);
    k_fillb<<<nbuk, 256, 0, stream>>>(upairs, hscan, bsum, csr, startv, deg, cnt,
                                      E, N, nbuk);

    k_input<<<(N + 31) / 32, 512, 0, stream>>>(x, Win, bin, h16a, N);

    // layer 0
    k_aggr<<<(N + 3) / 4, 256, 0, stream>>>(startv, deg, csr, h16a, Z16, N);
    k_upd<false><<<nb64, 256, 0, stream>>>(h16a, Z16, cnt,
                                           ppk + 0 * 4096, ppk + 2 * 4096, ppk + 4 * 4096,
                                           nullptr, updb, bcomb, lng, lnb, h16b,
                                           nullptr, nullptr, nullptr, nullptr, N);

    // layer 1 (fused MFMA out-MLP -> d_out)
    k_aggr<<<(N + 3) / 4, 256, 0, stream>>>(startv, deg, csr, h16b, Z16, N);
    k_upd<true><<<nb64, 256, 0, stream>>>(h16b, Z16, cnt,
                                          ppk + 1 * 4096, ppk + 3 * 4096, ppk + 5 * 4096,
                                          opk, updb + H, bcomb + H, lng + H, lnb + H,
                                          nullptr, b1, W2, b2, (float*)d_out, N);
}